// Round 8
// baseline (471.577 us; speedup 1.0000x reference)
//
#include <hip/hip_runtime.h>

// RNNCell scan: T=512, B=16384, H=32.
// 8 batches/wave -> 2048 waves = 2 waves/SIMD (TLP hides the serial chain).
// Nonlinear work in compact layout (batch = lane&7, h = 4*(lane>>3)+i).
// MFMA B-fragments rebuilt from the compact layout with row_ror:8 DPP +
// cndmask on the VALU pipe. Compact layout == tile-select((lane>>3)&1) of
// the MFMA D layout, so post-GEMM select is cheap and the epilogue needs
// no redistribution. bf16 hi/lo trunc split (v_perm packing).
// FLAT MFMA: each GEMM's three products (hh, h*lo, lo*h) are issued as
// INDEPENDENT MFMAs (1-deep) and combined with packed f32 adds — the old
// 3-deep dependent accumulator chain put 3x MFMA latency on the serial
// gamma path, which the 2 near-lockstep waves/SIMD could not cover
// (r7: freeing issue slots didn't move wall; dual-stall ~680 cy/step).
// -log2e folded into GEMM1's A/bias; W3 folded into GEMM2's A at setup.
// Cross-lane reduce: ror8 DPP + permlane16_swap + permlane32_swap (VALU).
// PACKED-F32: paired scalar math as ext_vector(2) float -> v_pk_* VOP3P.
// p0 store deferred one iteration.
// NOTE: amdgpu_waves_per_eu(2,2) is BANNED here — it produced post-timing
// output divergence (absmax 0.18) with zero perf gain (r6). Mechanism
// unexplained; __launch_bounds__(256,2) is the verified-correct form.

#define T_STEPS 512
#define B_TOT   16384
#define STRIDE_B 65536            // B_TOT * sizeof(float)

typedef __attribute__((ext_vector_type(8))) short short8;
typedef __attribute__((ext_vector_type(4))) float f32x4;
typedef __attribute__((ext_vector_type(2))) float f32x2;
typedef __attribute__((ext_vector_type(4))) int   i32x4;
typedef __attribute__((ext_vector_type(2))) unsigned int uint2v;

__device__ __forceinline__ short8 as_s8(i32x4 v) {
    union { i32x4 i; short8 s; } u; u.i = v; return u.s;
}

#define NLOG2E -1.44269504088896340736f
#define LN2     0.69314718055994530942f

// paired softplus + sigmoid sharing one exp each:
// sp(z) = z - ln(sigma(z)); interiors packed (pk_mul / pk_add / pk_fma).
__device__ __forceinline__ void sp_sig2(f32x2 z, f32x2& sp, f32x2& sg) {
    const f32x2 zs = z * NLOG2E;                    // v_pk_mul_f32
    f32x2 t;
    t[0] = __builtin_amdgcn_exp2f(zs[0]);
    t[1] = __builtin_amdgcn_exp2f(zs[1]);
    const f32x2 u = t + 1.0f;                       // v_pk_add_f32
    f32x2 r;
    r[0] = __builtin_amdgcn_rcpf(u[0]);
    r[1] = __builtin_amdgcn_rcpf(u[1]);
    sg = r;
    f32x2 lg;
    lg[0] = __builtin_amdgcn_logf(r[0]);
    lg[1] = __builtin_amdgcn_logf(r[1]);
    const f32x2 nl2 = {-LN2, -LN2};
    sp = __builtin_elementwise_fma(lg, nl2, z);     // v_pk_fma_f32
}

// paired sigmoid from pre-scaled zs = -log2e * z
__device__ __forceinline__ f32x2 sigm2v(f32x2 zs) {
    f32x2 t;
    t[0] = __builtin_amdgcn_exp2f(zs[0]);
    t[1] = __builtin_amdgcn_exp2f(zs[1]);
    const f32x2 u = t + 1.0f;                       // v_pk_add_f32
    f32x2 r;
    r[0] = __builtin_amdgcn_rcpf(u[0]);
    r[1] = __builtin_amdgcn_rcpf(u[1]);
    return r;
}

// exact trunc split of a pair, v_perm packing; residual sub packed.
__device__ __forceinline__ void sp2tv(f32x2 x, int& hi, int& lo) {
    const unsigned u0 = __float_as_uint(x[0]);
    const unsigned u1 = __float_as_uint(x[1]);
    hi = (int)__builtin_amdgcn_perm(u1, u0, 0x07060302u);
    f32x2 h;
    h[0] = __uint_as_float(u0 & 0xffff0000u);
    h[1] = __uint_as_float(u1 & 0xffff0000u);
    const f32x2 l = x - h;                          // v_pk_add_f32 (neg)
    lo = (int)__builtin_amdgcn_perm(__float_as_uint(l[1]), __float_as_uint(l[0]),
                                    0x07060302u);
}

// row_ror:8 — swap the two 8-lane halves of each 16-lane row (VALU pipe)
__device__ __forceinline__ int ror8(int x) {
    return __builtin_amdgcn_update_dpp(0, x, 0x128, 0xF, 0xF, 1);
}
__device__ __forceinline__ float ror8f(float x) {
    return __int_as_float(ror8(__float_as_int(x)));
}

// butterfly xor16 / xor32 sums via gfx950 permlane swaps (VALU pipe).
__device__ __forceinline__ float sum16(float x) {
    const uint2v r = __builtin_amdgcn_permlane16_swap(
        __float_as_uint(x), __float_as_uint(x), false, false);
    return __uint_as_float(r[0]) + __uint_as_float(r[1]);
}
__device__ __forceinline__ float sum32(float x) {
    const uint2v r = __builtin_amdgcn_permlane32_swap(
        __float_as_uint(x), __float_as_uint(x), false, false);
    return __uint_as_float(r[0]) + __uint_as_float(r[1]);
}

#define MFMA(A, B, C) __builtin_amdgcn_mfma_f32_16x16x32_bf16((A), (B), (C), 0, 0, 0)

__global__ __launch_bounds__(256, 2) void rnn_scan(
    const float* __restrict__ eps, const float* __restrict__ hs,
    const float* __restrict__ W1,  const float* __restrict__ b1,
    const float* __restrict__ W2,  const float* __restrict__ b2,
    const float* __restrict__ W3,  float* __restrict__ out)
{
    const int lane = threadIdx.x & 63;
    const int wv   = threadIdx.x >> 6;
    const int bat  = lane & 7;           // batch within wave
    const int hg   = lane >> 3;          // compact h-group: h = 4*hg + i
    const int c    = lane & 15;          // MFMA column
    const int q    = lane >> 4;          // MFMA quad
    const int bidx = blockIdx.x * 32 + wv * 8 + bat;

    // compact-layout per-lane weights as i-pairs (h = 4*hg + {0,1} / {2,3})
    const int h0 = 4 * hg;
    const f32x2 W1eP0 = {W1[h0 + 0],      W1[h0 + 1]};
    const f32x2 W1eP1 = {W1[h0 + 2],      W1[h0 + 3]};
    const f32x2 W1gP0 = {W1[32 + h0 + 0], W1[32 + h0 + 1]};
    const f32x2 W1gP1 = {W1[32 + h0 + 2], W1[32 + h0 + 3]};
    const f32x2 b1Pa  = {b1[h0 + 0],      b1[h0 + 1]};
    const f32x2 b1Pb  = {b1[h0 + 2],      b1[h0 + 3]};

    // D-layout b2 (h = 8q + i), pre-scaled by -log2e, persistent MFMA C.
    f32x4 B2V0, B2V1;
#pragma unroll
    for (int i = 0; i < 4; ++i) {
        B2V0[i] = b2[8 * q + i] * NLOG2E;
        B2V1[i] = b2[8 * q + 4 + i] * NLOG2E;
    }
    const f32x4 ZV = {0.f, 0.f, 0.f, 0.f};

    // A fragments (hi/lo trunc split), row-permuted h(m,t)=8*(m>>2)+4t+(m&3).
    // A1 (GEMM1, z2^T = W2^T@a1^T) pre-scaled by -log2e.
    // A2 (GEMM2, s = W2@diag(W3)@sig) has W3 folded in per-k.
    i32x4 A1h[2], A1l[2], A2h[2], A2l[2];
#pragma unroll
    for (int t = 0; t < 2; ++t) {
        const int hc = 8 * (c >> 2) + 4 * t + (c & 3);
#pragma unroll
        for (int p = 0; p < 4; ++p) {
            int th, tl;
            const int k0 = 8 * q + 2 * p, k1 = k0 + 1;
            const f32x2 x = {W2[k0 * 32 + hc] * NLOG2E,
                             W2[k1 * 32 + hc] * NLOG2E};
            sp2tv(x, th, tl);
            A1h[t][p] = th; A1l[t][p] = tl;
            const f32x2 y = {W2[hc * 32 + k0] * W3[k0],
                             W2[hc * 32 + k1] * W3[k1]};
            sp2tv(y, th, tl);
            A2h[t][p] = th; A2l[t][p] = tl;
        }
    }

    const bool hiHalf = (c & 8) != 0;    // this lane sits in row-half 8..15
    const bool tsel   = (hg & 1) != 0;   // which D-tile this lane owns

    float gamma = 0.0f;
    float h_cur = hs[bidx];
    f32x2 preA, preB;
    {
        const float e0 = eps[bidx];
        const f32x2 ev = {e0, e0};
        preA = __builtin_elementwise_fma(ev, W1eP0, b1Pa);
        preB = __builtin_elementwise_fma(ev, W1eP1, b1Pb);
    }
    int voff_ld = bidx * 4 + STRIDE_B;   // loads for step t+1
    int voff_st = bidx * 4;              // store for step t-1
    float p0_pend = 0.0f;

#define STEP_BODY(PF, ST)                                                      \
    {                                                                          \
        if (ST) {                                                              \
            *(float*)((char*)out + voff_st) = p0_pend;                         \
            voff_st += STRIDE_B;                                               \
        }                                                                      \
        float e_nxt = 0.f, h_nxt = 0.f;                                        \
        if (PF) {                                                              \
            e_nxt = *(const float*)((const char*)eps + voff_ld);               \
            h_nxt = *(const float*)((const char*)hs + voff_ld);                \
            voff_ld += STRIDE_B;                                               \
        }                                                                      \
        /* z1 = pre + gamma*W1g (pk_fma); a1 = softplus, g1 = sigmoid */       \
        const f32x2 gv = {gamma, gamma};                                       \
        const f32x2 z1a = __builtin_elementwise_fma(gv, W1gP0, preA);          \
        const f32x2 z1b = __builtin_elementwise_fma(gv, W1gP1, preB);          \
        f32x2 a1a, g1a, a1b, g1b;                                              \
        sp_sig2(z1a, a1a, g1a);                                                \
        sp_sig2(z1b, a1b, g1b);                                                \
        int H0, L0, H1, L1;                                                    \
        sp2tv(a1a, H0, L0);                                                    \
        sp2tv(a1b, H1, L1);                                                    \
        /* B fragment from compact layout: row-half swap via DPP + select */   \
        i32x4 bh, bl;                                                          \
        {                                                                      \
            const int rH0 = ror8(H0), rH1 = ror8(H1);                          \
            const int rL0 = ror8(L0), rL1 = ror8(L1);                          \
            bh[0] = hiHalf ? rH0 : H0;  bh[1] = hiHalf ? rH1 : H1;             \
            bh[2] = hiHalf ? H0 : rH0;  bh[3] = hiHalf ? H1 : rH1;             \
            bl[0] = hiHalf ? rL0 : L0;  bl[1] = hiHalf ? rL1 : L1;             \
            bl[2] = hiHalf ? L0 : rL0;  bl[3] = hiHalf ? L1 : rL1;             \
        }                                                                      \
        /* GEMM1 (pre-scaled): zs2 = -log2e*(W2^T a1 + b2).                   */\
        /* FLAT: hh / h*lo / lo*h issued as independent MFMAs (pipeline,      */\
        /* ~5cy apart), combined with packed adds — 1x MFMA latency on the    */\
        /* serial path instead of 3x.                                         */\
        const short8 Bh = as_s8(bh), Bl = as_s8(bl);                           \
        const f32x4 zA = MFMA(as_s8(A1h[0]), Bh, B2V0);                        \
        const f32x4 zB = MFMA(as_s8(A1h[1]), Bh, B2V1);                        \
        const f32x4 zC = MFMA(as_s8(A1h[0]), Bl, ZV);                          \
        const f32x4 zD = MFMA(as_s8(A1h[1]), Bl, ZV);                          \
        const f32x4 zE = MFMA(as_s8(A1l[0]), Bh, ZV);                          \
        const f32x4 zF = MFMA(as_s8(A1l[1]), Bh, ZV);                          \
        const f32x4 z0 = (zA + zC) + zE;                                       \
        const f32x4 z1 = (zB + zD) + zF;                                       \
        /* tile-select to compact; v2 = sigm(z2) (W3 folded into A2) */        \
        const f32x2 zselA = {tsel ? z1[0] : z0[0], tsel ? z1[1] : z0[1]};      \
        const f32x2 zselB = {tsel ? z1[2] : z0[2], tsel ? z1[3] : z0[3]};      \
        const f32x2 v2a = sigm2v(zselA);                                       \
        const f32x2 v2b = sigm2v(zselB);                                       \
        sp2tv(v2a, H0, L0);                                                    \
        sp2tv(v2b, H1, L1);                                                    \
        i32x4 vh, vl;                                                          \
        {                                                                      \
            const int rH0 = ror8(H0), rH1 = ror8(H1);                          \
            const int rL0 = ror8(L0), rL1 = ror8(L1);                          \
            vh[0] = hiHalf ? rH0 : H0;  vh[1] = hiHalf ? rH1 : H1;             \
            vh[2] = hiHalf ? H0 : rH0;  vh[3] = hiHalf ? H1 : rH1;             \
            vl[0] = hiHalf ? rL0 : L0;  vl[1] = hiHalf ? rL1 : L1;             \
            vl[2] = hiHalf ? L0 : rL0;  vl[3] = hiHalf ? L1 : rL1;             \
        }                                                                      \
        /* GEMM2 (W3-folded): s = W2 diag(W3) sig — FLAT, same scheme */       \
        const short8 Vh = as_s8(vh), Vl = as_s8(vl);                           \
        const f32x4 sA = MFMA(as_s8(A2h[0]), Vh, ZV);                          \
        const f32x4 sB = MFMA(as_s8(A2h[1]), Vh, ZV);                          \
        const f32x4 sC = MFMA(as_s8(A2h[0]), Vl, ZV);                          \
        const f32x4 sD = MFMA(as_s8(A2h[1]), Vl, ZV);                          \
        const f32x4 sE = MFMA(as_s8(A2l[0]), Vh, ZV);                          \
        const f32x4 sF = MFMA(as_s8(A2l[1]), Vh, ZV);                          \
        const f32x4 s0 = (sA + sC) + sE;                                       \
        const f32x4 s1 = (sB + sD) + sF;                                       \
        /* epilogue: v1 = g1.*s (pk_mul); p = v1@W1^T paired-across-i */       \
        const f32x2 seA = {tsel ? s1[0] : s0[0], tsel ? s1[1] : s0[1]};        \
        const f32x2 seB = {tsel ? s1[2] : s0[2], tsel ? s1[3] : s0[3]};        \
        const f32x2 vA = g1a * seA;                                            \
        const f32x2 vB = g1b * seB;                                            \
        f32x2 P0 = vA * W1eP0;                                                 \
        P0 = __builtin_elementwise_fma(vB, W1eP1, P0);                         \
        f32x2 P1 = vA * W1gP0;                                                 \
        P1 = __builtin_elementwise_fma(vB, W1gP1, P1);                         \
        float p0 = P0[0] + P0[1];                                              \
        float p1 = P1[0] + P1[1];                                              \
        /* reduce over the batch's 8 lanes (stride 8): xor8 via DPP, then */   \
        /* xor16/xor32 via permlane swaps — all VALU pipe, no DS latency */    \
        p1 += ror8f(p1);  p0 += ror8f(p0);                                     \
        p1 = sum16(p1);   p0 = sum16(p0);                                      \
        p1 = sum32(p1);   p0 = sum32(p0);                                      \
        p0_pend = p0;                    /* store deferred to next iter */     \
        gamma = fmaf(h_cur, -p1, gamma);                                       \
        h_cur = h_nxt;                                                         \
        if (PF) {                                                              \
            const f32x2 ev = {e_nxt, e_nxt};                                   \
            preA = __builtin_elementwise_fma(ev, W1eP0, b1Pa);                 \
            preB = __builtin_elementwise_fma(ev, W1eP1, b1Pb);                 \
        }                                                                      \
    }

    STEP_BODY(1, 0)                                      // t = 0
    for (int t = 1; t < T_STEPS - 1; ++t) STEP_BODY(1, 1)
    STEP_BODY(0, 1)                                      // t = 511
    *(float*)((char*)out + voff_st) = p0_pend;           // flush t = 511
#undef STEP_BODY
}

extern "C" void kernel_launch(void* const* d_in, const int* in_sizes, int n_in,
                              void* d_out, int out_size, void* d_ws, size_t ws_size,
                              hipStream_t stream) {
    const float* eps = (const float*)d_in[0];
    const float* hs  = (const float*)d_in[1];
    const float* W1  = (const float*)d_in[2];
    const float* b1  = (const float*)d_in[3];
    const float* W2  = (const float*)d_in[4];
    const float* b2  = (const float*)d_in[5];
    const float* W3  = (const float*)d_in[6];
    float* out = (float*)d_out;

    // 32 batches per 256-thread block (4 waves x 8) -> 512 blocks,
    // 2048 waves = 2 waves/SIMD
    dim3 grid(B_TOT / 32), block(256);
    hipLaunchKernelGGL(rnn_scan, grid, block, 0, stream,
                       eps, hs, W1, b1, W2, b2, W3, out);
}

// Round 9
// 445.359 us; speedup vs baseline: 1.0589x; 1.0589x over previous
//
#include <hip/hip_runtime.h>

// RNNCell scan: T=512, B=16384, H=32.
// 8 batches/wave -> 2048 waves = 2 waves/SIMD (TLP hides the serial chain).
// Nonlinear work in compact layout (batch = lane&7, h = 4*(lane>>3)+i).
// MFMA B-fragments rebuilt from the compact layout with row_ror:8 DPP +
// cndmask on the VALU pipe. Compact layout == tile-select((lane>>3)&1) of
// the MFMA D layout, so post-GEMM select is cheap and the epilogue needs
// no redistribution. bf16 hi/lo trunc split (v_perm packing), 3 MFMAs/tile
// (3-deep dependent accumulate — r8 proved flattening it costs issue for
// zero latency win).
// -log2e folded into GEMM1's A/bias; W3 folded into GEMM2's A at setup.
// Cross-lane reduce: ror8 DPP + permlane16_swap + permlane32_swap (VALU).
// PACKED-F32: paired scalar math as ext_vector(2) float -> v_pk_* VOP3P
// (r7: -8 VALU pts issue, wall-neutral alone; pays off once stalls covered).
// DE-LOCKSTEP STAGGER (new): the 2 co-resident waves/SIMD come from 2
// blocks running the identical program in phase -> both stall on the same
// MFMA/exp chain regions simultaneously (r1/r7/r8 triangulation: wall =
// ~1320 issue + ~680 dual-stall cy/step). A one-time per-block random
// startup delay (0..~1790 cy) anti-aligns the stall windows so each wave
// covers the other's latency. Cost <1us one-time.
// p0 store deferred one iteration.
// NOTE: amdgpu_waves_per_eu(2,2) is BANNED here — post-timing output
// divergence (absmax 0.18) with zero perf gain (r6). Mechanism
// unexplained; __launch_bounds__(256,2) is the verified-correct form.

#define T_STEPS 512
#define B_TOT   16384
#define STRIDE_B 65536            // B_TOT * sizeof(float)

typedef __attribute__((ext_vector_type(8))) short short8;
typedef __attribute__((ext_vector_type(4))) float f32x4;
typedef __attribute__((ext_vector_type(2))) float f32x2;
typedef __attribute__((ext_vector_type(4))) int   i32x4;
typedef __attribute__((ext_vector_type(2))) unsigned int uint2v;

__device__ __forceinline__ short8 as_s8(i32x4 v) {
    union { i32x4 i; short8 s; } u; u.i = v; return u.s;
}

#define NLOG2E -1.44269504088896340736f
#define LN2     0.69314718055994530942f

// paired softplus + sigmoid sharing one exp each:
// sp(z) = z - ln(sigma(z)); interiors packed (pk_mul / pk_add / pk_fma).
__device__ __forceinline__ void sp_sig2(f32x2 z, f32x2& sp, f32x2& sg) {
    const f32x2 zs = z * NLOG2E;                    // v_pk_mul_f32
    f32x2 t;
    t[0] = __builtin_amdgcn_exp2f(zs[0]);
    t[1] = __builtin_amdgcn_exp2f(zs[1]);
    const f32x2 u = t + 1.0f;                       // v_pk_add_f32
    f32x2 r;
    r[0] = __builtin_amdgcn_rcpf(u[0]);
    r[1] = __builtin_amdgcn_rcpf(u[1]);
    sg = r;
    f32x2 lg;
    lg[0] = __builtin_amdgcn_logf(r[0]);
    lg[1] = __builtin_amdgcn_logf(r[1]);
    const f32x2 nl2 = {-LN2, -LN2};
    sp = __builtin_elementwise_fma(lg, nl2, z);     // v_pk_fma_f32
}

// paired sigmoid from pre-scaled zs = -log2e * z
__device__ __forceinline__ f32x2 sigm2v(f32x2 zs) {
    f32x2 t;
    t[0] = __builtin_amdgcn_exp2f(zs[0]);
    t[1] = __builtin_amdgcn_exp2f(zs[1]);
    const f32x2 u = t + 1.0f;                       // v_pk_add_f32
    f32x2 r;
    r[0] = __builtin_amdgcn_rcpf(u[0]);
    r[1] = __builtin_amdgcn_rcpf(u[1]);
    return r;
}

// exact trunc split of a pair, v_perm packing; residual sub packed.
__device__ __forceinline__ void sp2tv(f32x2 x, int& hi, int& lo) {
    const unsigned u0 = __float_as_uint(x[0]);
    const unsigned u1 = __float_as_uint(x[1]);
    hi = (int)__builtin_amdgcn_perm(u1, u0, 0x07060302u);
    f32x2 h;
    h[0] = __uint_as_float(u0 & 0xffff0000u);
    h[1] = __uint_as_float(u1 & 0xffff0000u);
    const f32x2 l = x - h;                          // v_pk_add_f32 (neg)
    lo = (int)__builtin_amdgcn_perm(__float_as_uint(l[1]), __float_as_uint(l[0]),
                                    0x07060302u);
}

// row_ror:8 — swap the two 8-lane halves of each 16-lane row (VALU pipe)
__device__ __forceinline__ int ror8(int x) {
    return __builtin_amdgcn_update_dpp(0, x, 0x128, 0xF, 0xF, 1);
}
__device__ __forceinline__ float ror8f(float x) {
    return __int_as_float(ror8(__float_as_int(x)));
}

// butterfly xor16 / xor32 sums via gfx950 permlane swaps (VALU pipe).
__device__ __forceinline__ float sum16(float x) {
    const uint2v r = __builtin_amdgcn_permlane16_swap(
        __float_as_uint(x), __float_as_uint(x), false, false);
    return __uint_as_float(r[0]) + __uint_as_float(r[1]);
}
__device__ __forceinline__ float sum32(float x) {
    const uint2v r = __builtin_amdgcn_permlane32_swap(
        __float_as_uint(x), __float_as_uint(x), false, false);
    return __uint_as_float(r[0]) + __uint_as_float(r[1]);
}

#define MFMA(A, B, C) __builtin_amdgcn_mfma_f32_16x16x32_bf16((A), (B), (C), 0, 0, 0)

__global__ __launch_bounds__(256, 2) void rnn_scan(
    const float* __restrict__ eps, const float* __restrict__ hs,
    const float* __restrict__ W1,  const float* __restrict__ b1,
    const float* __restrict__ W2,  const float* __restrict__ b2,
    const float* __restrict__ W3,  float* __restrict__ out)
{
    const int lane = threadIdx.x & 63;
    const int wv   = threadIdx.x >> 6;
    const int bat  = lane & 7;           // batch within wave
    const int hg   = lane >> 3;          // compact h-group: h = 4*hg + i
    const int c    = lane & 15;          // MFMA column
    const int q    = lane >> 4;          // MFMA quad
    const int bidx = blockIdx.x * 32 + wv * 8 + bat;

    // compact-layout per-lane weights as i-pairs (h = 4*hg + {0,1} / {2,3})
    const int h0 = 4 * hg;
    const f32x2 W1eP0 = {W1[h0 + 0],      W1[h0 + 1]};
    const f32x2 W1eP1 = {W1[h0 + 2],      W1[h0 + 3]};
    const f32x2 W1gP0 = {W1[32 + h0 + 0], W1[32 + h0 + 1]};
    const f32x2 W1gP1 = {W1[32 + h0 + 2], W1[32 + h0 + 3]};
    const f32x2 b1Pa  = {b1[h0 + 0],      b1[h0 + 1]};
    const f32x2 b1Pb  = {b1[h0 + 2],      b1[h0 + 3]};

    // D-layout b2 (h = 8q + i), pre-scaled by -log2e, persistent MFMA C.
    f32x4 B2V0, B2V1;
#pragma unroll
    for (int i = 0; i < 4; ++i) {
        B2V0[i] = b2[8 * q + i] * NLOG2E;
        B2V1[i] = b2[8 * q + 4 + i] * NLOG2E;
    }
    const f32x4 ZV = {0.f, 0.f, 0.f, 0.f};

    // A fragments (hi/lo trunc split), row-permuted h(m,t)=8*(m>>2)+4t+(m&3).
    // A1 (GEMM1, z2^T = W2^T@a1^T) pre-scaled by -log2e.
    // A2 (GEMM2, s = W2@diag(W3)@sig) has W3 folded in per-k.
    i32x4 A1h[2], A1l[2], A2h[2], A2l[2];
#pragma unroll
    for (int t = 0; t < 2; ++t) {
        const int hc = 8 * (c >> 2) + 4 * t + (c & 3);
#pragma unroll
        for (int p = 0; p < 4; ++p) {
            int th, tl;
            const int k0 = 8 * q + 2 * p, k1 = k0 + 1;
            const f32x2 x = {W2[k0 * 32 + hc] * NLOG2E,
                             W2[k1 * 32 + hc] * NLOG2E};
            sp2tv(x, th, tl);
            A1h[t][p] = th; A1l[t][p] = tl;
            const f32x2 y = {W2[hc * 32 + k0] * W3[k0],
                             W2[hc * 32 + k1] * W3[k1]};
            sp2tv(y, th, tl);
            A2h[t][p] = th; A2l[t][p] = tl;
        }
    }

    const bool hiHalf = (c & 8) != 0;    // this lane sits in row-half 8..15
    const bool tsel   = (hg & 1) != 0;   // which D-tile this lane owns

    float gamma = 0.0f;
    float h_cur = hs[bidx];
    f32x2 preA, preB;
    {
        const float e0 = eps[bidx];
        const f32x2 ev = {e0, e0};
        preA = __builtin_elementwise_fma(ev, W1eP0, b1Pa);
        preB = __builtin_elementwise_fma(ev, W1eP1, b1Pb);
    }
    int voff_ld = bidx * 4 + STRIDE_B;   // loads for step t+1
    int voff_st = bidx * 4;              // store for step t-1
    float p0_pend = 0.0f;

    // DE-LOCKSTEP: one-time per-block pseudo-random delay, 0..7 units of
    // ~256 cy. Co-resident blocks get (w.h.p.) different delays, so the two
    // waves sharing a SIMD run phase-offset and cover each other's
    // MFMA/exp-chain stalls instead of stalling together.
    {
        const unsigned hsh = (unsigned)blockIdx.x * 2654435761u;
        const int d = (hsh >> 24) & 7;
        for (int i = 0; i < d; ++i) __builtin_amdgcn_s_sleep(4);
    }

#define STEP_BODY(PF, ST)                                                      \
    {                                                                          \
        if (ST) {                                                              \
            *(float*)((char*)out + voff_st) = p0_pend;                         \
            voff_st += STRIDE_B;                                               \
        }                                                                      \
        float e_nxt = 0.f, h_nxt = 0.f;                                        \
        if (PF) {                                                              \
            e_nxt = *(const float*)((const char*)eps + voff_ld);               \
            h_nxt = *(const float*)((const char*)hs + voff_ld);                \
            voff_ld += STRIDE_B;                                               \
        }                                                                      \
        /* z1 = pre + gamma*W1g (pk_fma); a1 = softplus, g1 = sigmoid */       \
        const f32x2 gv = {gamma, gamma};                                       \
        const f32x2 z1a = __builtin_elementwise_fma(gv, W1gP0, preA);          \
        const f32x2 z1b = __builtin_elementwise_fma(gv, W1gP1, preB);          \
        f32x2 a1a, g1a, a1b, g1b;                                              \
        sp_sig2(z1a, a1a, g1a);                                                \
        sp_sig2(z1b, a1b, g1b);                                                \
        int H0, L0, H1, L1;                                                    \
        sp2tv(a1a, H0, L0);                                                    \
        sp2tv(a1b, H1, L1);                                                    \
        /* B fragment from compact layout: row-half swap via DPP + select */   \
        i32x4 bh, bl;                                                          \
        {                                                                      \
            const int rH0 = ror8(H0), rH1 = ror8(H1);                          \
            const int rL0 = ror8(L0), rL1 = ror8(L1);                          \
            bh[0] = hiHalf ? rH0 : H0;  bh[1] = hiHalf ? rH1 : H1;             \
            bh[2] = hiHalf ? H0 : rH0;  bh[3] = hiHalf ? H1 : rH1;             \
            bl[0] = hiHalf ? rL0 : L0;  bl[1] = hiHalf ? rL1 : L1;             \
            bl[2] = hiHalf ? L0 : rL0;  bl[3] = hiHalf ? L1 : rL1;             \
        }                                                                      \
        /* GEMM1 (pre-scaled): zs2 = -log2e*(W2^T a1 + b2); 3-deep chains,    */\
        /* C seeded from persistent B2V0/B2V1 (no movs)                       */\
        const short8 Bh = as_s8(bh), Bl = as_s8(bl);                           \
        f32x4 z0 = MFMA(as_s8(A1h[0]), Bh, B2V0);                              \
        f32x4 z1 = MFMA(as_s8(A1h[1]), Bh, B2V1);                              \
        z0 = MFMA(as_s8(A1h[0]), Bl, z0);                                      \
        z1 = MFMA(as_s8(A1h[1]), Bl, z1);                                      \
        z0 = MFMA(as_s8(A1l[0]), Bh, z0);                                      \
        z1 = MFMA(as_s8(A1l[1]), Bh, z1);                                      \
        /* tile-select to compact; v2 = sigm(z2) (W3 folded into A2) */        \
        const f32x2 zselA = {tsel ? z1[0] : z0[0], tsel ? z1[1] : z0[1]};      \
        const f32x2 zselB = {tsel ? z1[2] : z0[2], tsel ? z1[3] : z0[3]};      \
        const f32x2 v2a = sigm2v(zselA);                                       \
        const f32x2 v2b = sigm2v(zselB);                                       \
        sp2tv(v2a, H0, L0);                                                    \
        sp2tv(v2b, H1, L1);                                                    \
        i32x4 vh, vl;                                                          \
        {                                                                      \
            const int rH0 = ror8(H0), rH1 = ror8(H1);                          \
            const int rL0 = ror8(L0), rL1 = ror8(L1);                          \
            vh[0] = hiHalf ? rH0 : H0;  vh[1] = hiHalf ? rH1 : H1;             \
            vh[2] = hiHalf ? H0 : rH0;  vh[3] = hiHalf ? H1 : rH1;             \
            vl[0] = hiHalf ? rL0 : L0;  vl[1] = hiHalf ? rL1 : L1;             \
            vl[2] = hiHalf ? L0 : rL0;  vl[3] = hiHalf ? L1 : rL1;             \
        }                                                                      \
        /* GEMM2 (W3-folded): s = W2 diag(W3) sig; C seeded from ZV */         \
        const short8 Vh = as_s8(vh), Vl = as_s8(vl);                           \
        f32x4 s0 = MFMA(as_s8(A2h[0]), Vh, ZV);                                \
        f32x4 s1 = MFMA(as_s8(A2h[1]), Vh, ZV);                                \
        s0 = MFMA(as_s8(A2h[0]), Vl, s0);                                      \
        s1 = MFMA(as_s8(A2h[1]), Vl, s1);                                      \
        s0 = MFMA(as_s8(A2l[0]), Vh, s0);                                      \
        s1 = MFMA(as_s8(A2l[1]), Vh, s1);                                      \
        /* epilogue: v1 = g1.*s (pk_mul); p = v1@W1^T paired-across-i */       \
        const f32x2 seA = {tsel ? s1[0] : s0[0], tsel ? s1[1] : s0[1]};        \
        const f32x2 seB = {tsel ? s1[2] : s0[2], tsel ? s1[3] : s0[3]};        \
        const f32x2 vA = g1a * seA;                                            \
        const f32x2 vB = g1b * seB;                                            \
        f32x2 P0 = vA * W1eP0;                                                 \
        P0 = __builtin_elementwise_fma(vB, W1eP1, P0);                         \
        f32x2 P1 = vA * W1gP0;                                                 \
        P1 = __builtin_elementwise_fma(vB, W1gP1, P1);                         \
        float p0 = P0[0] + P0[1];                                              \
        float p1 = P1[0] + P1[1];                                              \
        /* reduce over the batch's 8 lanes (stride 8): xor8 via DPP, then */   \
        /* xor16/xor32 via permlane swaps — all VALU pipe, no DS latency */    \
        p1 += ror8f(p1);  p0 += ror8f(p0);                                     \
        p1 = sum16(p1);   p0 = sum16(p0);                                      \
        p1 = sum32(p1);   p0 = sum32(p0);                                      \
        p0_pend = p0;                    /* store deferred to next iter */     \
        gamma = fmaf(h_cur, -p1, gamma);                                       \
        h_cur = h_nxt;                                                         \
        if (PF) {                                                              \
            const f32x2 ev = {e_nxt, e_nxt};                                   \
            preA = __builtin_elementwise_fma(ev, W1eP0, b1Pa);                 \
            preB = __builtin_elementwise_fma(ev, W1eP1, b1Pb);                 \
        }                                                                      \
    }

    STEP_BODY(1, 0)                                      // t = 0
    for (int t = 1; t < T_STEPS - 1; ++t) STEP_BODY(1, 1)
    STEP_BODY(0, 1)                                      // t = 511
    *(float*)((char*)out + voff_st) = p0_pend;           // flush t = 511
#undef STEP_BODY
}

extern "C" void kernel_launch(void* const* d_in, const int* in_sizes, int n_in,
                              void* d_out, int out_size, void* d_ws, size_t ws_size,
                              hipStream_t stream) {
    const float* eps = (const float*)d_in[0];
    const float* hs  = (const float*)d_in[1];
    const float* W1  = (const float*)d_in[2];
    const float* b1  = (const float*)d_in[3];
    const float* W2  = (const float*)d_in[4];
    const float* b2  = (const float*)d_in[5];
    const float* W3  = (const float*)d_in[6];
    float* out = (float*)d_out;

    // 32 batches per 256-thread block (4 waves x 8) -> 512 blocks,
    // 2048 waves = 2 waves/SIMD
    dim3 grid(B_TOT / 32), block(256);
    hipLaunchKernelGGL(rnn_scan, grid, block, 0, stream,
                       eps, hs, W1, b1, W2, b2, W3, out);
}